// Round 13
// baseline (153.015 us; speedup 1.0000x reference)
//
#include <hip/hip_runtime.h>
#include <stdint.h>
#include <math.h>

// PhysicsForwardModel: B=2, Nz=Nx=128, Ly=Lx=512.
// out[b,t,l] = (1/3) * sum_j Cy[j,l] * sum_k cos(F[k,j]*t) * a[k] * (Cy[:,:128] x[b] Cy[:,128:256]^T)[k,j]
//              + std_b * N(0,1)  (JAX threefry key=42, partitionable counters, XLA erfinv)
// R13: trans pipe = 2 lanes/cyc/SIMD (calibrated R9/R11/R12). Phase C cos halved via
// angle addition (1 cos+1 sin covers t0, t0+128, t0+256, t0+384); phase B cos
// eliminated via Chebyshev 3-term recurrence. k-quartered grid keeps 4 waves/SIMD;
// 4 partial V arrays summed in stageC's gather.

#define HALF_N 262144  // 512*512 per-batch elements
#define PI_F 3.14159274101257324f

// ws layout (floats): Cy [0..262144) [k][n]; Vt 4 partials [262144..2359296);
//                     partial [2359296..2361344)

__device__ __forceinline__ uint32_t rotl32(uint32_t v, int r) {
  return (v << r) | (v >> (32 - r));
}

// XLA ErfInv32 (Giles) -- matches reference's lax.erf_inv
__device__ __forceinline__ float erfinv_xla(float x) {
  float w = -log1pf(__fmul_rn(-x, x));
  float p;
  if (w < 5.0f) {
    w = w - 2.5f;
    p = 2.81022636e-08f;
    p = fmaf(p, w, 3.43273939e-07f);
    p = fmaf(p, w, -3.5233877e-06f);
    p = fmaf(p, w, -4.39150654e-06f);
    p = fmaf(p, w, 0.00021858087f);
    p = fmaf(p, w, -0.00125372503f);
    p = fmaf(p, w, -0.00417768164f);
    p = fmaf(p, w, 0.246640727f);
    p = fmaf(p, w, 1.50140941f);
  } else {
    w = __fsqrt_rn(w) - 3.0f;
    p = -0.000200214257f;
    p = fmaf(p, w, 0.000100950558f);
    p = fmaf(p, w, 0.00134934322f);
    p = fmaf(p, w, -0.00367342844f);
    p = fmaf(p, w, 0.00573950773f);
    p = fmaf(p, w, -0.0076224613f);
    p = fmaf(p, w, 0.00943887047f);
    p = fmaf(p, w, 1.00167406f);
    p = fmaf(p, w, 2.83297682f);
  }
  return p * x;
}

// Cy[k,n] = sc(k) * 2 * cos(pi*(2n+1)*k/1024)
__device__ __forceinline__ float cy_elem(float n2p1, float kf, float sc) {
  float t1 = __fmul_rn(PI_F, n2p1);
  float arg = __fmul_rn(t1, kf) * (1.0f / 1024.0f);
  return __fmul_rn(sc, __fmul_rn(2.0f, __cosf(arg)));
}

// Materialize Cy [k][n] for stageC + stageB phase A row loads.
__global__ __launch_bounds__(256) void init_kernel(float* __restrict__ Cy) {
  int idx = blockIdx.x * 256 + threadIdx.x;  // < 262144
  const float s0c = 1.0f / __fsqrt_rn(2048.0f);
  int k = idx >> 9, n = idx & 511;
  float sc = (k == 0) ? s0c : 0.03125f;
  Cy[idx] = cy_elem((float)(2 * n + 1), (float)k, sc);
}

// stageB, block = (j, kq) (grid 2048, 128 threads):
//   A  : cyl[jj] = Cy[j,128+jj]  (table row load)
//   A2 : us[b*128+i] = sum_jj x[b,i,jj]*cyl[jj]   (each lane 2 rows)
//   B  : lane k=kq*128+tid: m[b,k] via Chebyshev recurrence over i (no cos);
//        f + shift constants cos/sin(128f),(256f) analytic; -> 2 LDS float4/k
//   C  : lane t0: 1 cos + 1 sin covers t0,+128,+256,+384; acc 4x2; write partial
__global__ __launch_bounds__(128) void stageB_kernel(const float* __restrict__ x,
                                                     const float* __restrict__ Cy,
                                                     float* __restrict__ Vt) {
  __shared__ float cyl[128];
  __shared__ float us[256];
  __shared__ float4 ldsA[128];  // {f, c1, s1, m0}
  __shared__ float4 ldsB[128];  // {c2, s2, m1, pad}
  int j = blockIdx.x >> 2;
  int kq = blockIdx.x & 3;
  int tid = threadIdx.x;
  float jf = (float)j;
  const float s0c = 1.0f / __fsqrt_rn(2048.0f);
  cyl[tid] = Cy[(j << 9) + 128 + tid];
  __syncthreads();
#pragma unroll
  for (int r = 0; r < 2; ++r) {
    int row = tid + (r << 7);
    int b = row >> 7, i = row & 127;
    const float* xr = x + (b * 128 + i) * 128;
    float accA = 0.0f, accB = 0.0f;
    for (int jj = 0; jj < 128; jj += 8) {
      float4 xa = *(const float4*)&xr[jj];
      float4 xb = *(const float4*)&xr[jj + 4];
      float4 ca = *(const float4*)&cyl[jj];
      float4 cb = *(const float4*)&cyl[jj + 4];
      accA = fmaf(xa.x, ca.x, accA); accB = fmaf(xa.y, ca.y, accB);
      accA = fmaf(xa.z, ca.z, accA); accB = fmaf(xa.w, ca.w, accB);
      accA = fmaf(xb.x, cb.x, accA); accB = fmaf(xb.y, cb.y, accB);
      accA = fmaf(xb.z, cb.z, accA); accB = fmaf(xb.w, cb.w, accB);
    }
    us[row] = accA + accB;
  }
  __syncthreads();
  {
    int k = (kq << 7) + tid;
    float kf = (float)k;
    const float w0 = PI_F / 512.0f;  // exact pow2 scale
    float ky = __fmul_rn(kf, w0);    // = recurrence step D (pi*k/512)
    float kx = __fmul_rn(jf, w0);
    float f = __fsqrt_rn(__fadd_rn(__fmul_rn(ky, ky), __fmul_rn(kx, kx)));
    // shift constants: cos/sin(128f), derived 256f
    float a128 = __fmul_rn(f, 128.0f);
    float c1 = __cosf(a128), s1 = __sinf(a128);
    float c2 = fmaf(c1, c1, -s1 * s1);
    float s2 = 2.0f * s1 * c1;
    // Chebyshev: theta_i = (2i+1)*pi*k/1024; theta_0 = ky/2; step = ky; c_{-1}=c_0
    float c0i = __cosf(__fmul_rn(ky, 0.5f));
    float d = __fmul_rn(2.0f, __cosf(ky));
    float sc = (k == 0) ? s0c : 0.03125f;
    float a_k = __fmul_rn(sc, __fmul_rn(2.0f, c0i));  // a[k] = Cy[k,0]
    float cm1 = c0i, cc = c0i;
    float r0 = cc * us[0], r1 = cc * us[128];
    for (int i = 1; i < 128; ++i) {
      float cn = fmaf(d, cc, -cm1);
      cm1 = cc; cc = cn;
      r0 = fmaf(cc, us[i], r0);
      r1 = fmaf(cc, us[128 + i], r1);
    }
    float s2x = __fmul_rn(sc, 2.0f);
    float m0 = __fmul_rn(a_k, __fmul_rn(s2x, r0));
    float m1 = __fmul_rn(a_k, __fmul_rn(s2x, r1));
    ldsA[tid] = make_float4(f, c1, s1, m0);
    ldsB[tid] = make_float4(c2, s2, m1, 0.0f);
  }
  __syncthreads();
  float tf = (float)tid;  // t0 < 128
  float a0b0 = 0.f, a1b0 = 0.f, a2b0 = 0.f, a3b0 = 0.f;
  float a0b1 = 0.f, a1b1 = 0.f, a2b1 = 0.f, a3b1 = 0.f;
  for (int kl = 0; kl < 128; kl += 2) {
    float4 A0 = ldsA[kl];
    float4 B0 = ldsB[kl];
    float4 A1 = ldsA[kl + 1];
    float4 B1 = ldsB[kl + 1];
    float ag0 = __fmul_rn(A0.x, tf);  // bit-matches ref's f32 F*t for t<128
    float ag1 = __fmul_rn(A1.x, tf);
    float c00 = __cosf(ag0), s00 = __sinf(ag0);
    float c01 = __cosf(ag1), s01 = __sinf(ag1);
    // k #0: c3 = c1c2-s1s2, s3 = s1c2+c1s2 (recompute, cheaper than 3rd LDS read)
    {
      float c3 = fmaf(A0.y, B0.x, -A0.z * B0.y);
      float s3 = fmaf(A0.z, B0.x, A0.y * B0.y);
      float p1 = fmaf(c00, A0.y, -s00 * A0.z);
      float p2 = fmaf(c00, B0.x, -s00 * B0.y);
      float p3 = fmaf(c00, c3, -s00 * s3);
      a0b0 = fmaf(c00, A0.w, a0b0); a0b1 = fmaf(c00, B0.z, a0b1);
      a1b0 = fmaf(p1, A0.w, a1b0);  a1b1 = fmaf(p1, B0.z, a1b1);
      a2b0 = fmaf(p2, A0.w, a2b0);  a2b1 = fmaf(p2, B0.z, a2b1);
      a3b0 = fmaf(p3, A0.w, a3b0);  a3b1 = fmaf(p3, B0.z, a3b1);
    }
    // k #1
    {
      float c3 = fmaf(A1.y, B1.x, -A1.z * B1.y);
      float s3 = fmaf(A1.z, B1.x, A1.y * B1.y);
      float p1 = fmaf(c01, A1.y, -s01 * A1.z);
      float p2 = fmaf(c01, B1.x, -s01 * B1.y);
      float p3 = fmaf(c01, c3, -s01 * s3);
      a0b0 = fmaf(c01, A1.w, a0b0); a0b1 = fmaf(c01, B1.z, a0b1);
      a1b0 = fmaf(p1, A1.w, a1b0);  a1b1 = fmaf(p1, B1.z, a1b1);
      a2b0 = fmaf(p2, A1.w, a2b0);  a2b1 = fmaf(p2, B1.z, a2b1);
      a3b0 = fmaf(p3, A1.w, a3b0);  a3b1 = fmaf(p3, B1.z, a3b1);
    }
  }
  float* vb = Vt + (kq * 524288) + (j << 10) + tid;
  vb[0]   = a0b0; vb[128] = a1b0; vb[256] = a2b0; vb[384] = a3b0;
  vb[512] = a0b1; vb[640] = a1b1; vb[768] = a2b1; vb[896] = a3b1;
}

// stageC: out[b,t,l] = (1/3) * sum_j Cy[j,l] * (sum of 4 k-partials)[j,b,t]
__global__ __launch_bounds__(256, 4) void stageC_kernel(const float* __restrict__ Cy,
                                                        const float* __restrict__ Vt,
                                                        float* __restrict__ out,
                                                        float* __restrict__ partial) {
  __shared__ float vq[2048];  // [j][4] = {b0t0, b1t0, b0t1, b1t1}
  int tpair = blockIdx.x >> 1;
  int lhalf = blockIdx.x & 1;
  int t0 = tpair << 1;
  int tid = threadIdx.x;
#pragma unroll
  for (int r = 0; r < 2; ++r) {
    int j = tid + (r << 8);
    const float* base = Vt + (j << 10);
    float v0 = 0.f, v1 = 0.f, v2 = 0.f, v3 = 0.f;
#pragma unroll
    for (int kq = 0; kq < 4; ++kq) {
      const float* p = base + kq * 524288;
      v0 += p[t0];
      v1 += p[512 + t0];
      v2 += p[t0 + 1];
      v3 += p[512 + t0 + 1];
    }
    vq[(j << 2) + 0] = v0;
    vq[(j << 2) + 1] = v1;
    vq[(j << 2) + 2] = v2;
    vq[(j << 2) + 3] = v3;
  }
  __syncthreads();
  int l = (lhalf << 8) + tid;
  float a00 = 0.f, a01 = 0.f, a10 = 0.f, a11 = 0.f;
  for (int j = 0; j < 512; j += 4) {
    float c0 = Cy[(j << 9) + l];
    float c1 = Cy[((j + 1) << 9) + l];
    float c2 = Cy[((j + 2) << 9) + l];
    float c3 = Cy[((j + 3) << 9) + l];
    float4 va = *(const float4*)&vq[j << 2];
    float4 vb = *(const float4*)&vq[(j + 1) << 2];
    float4 vc = *(const float4*)&vq[(j + 2) << 2];
    float4 vd = *(const float4*)&vq[(j + 3) << 2];
    a00 = fmaf(c0, va.x, a00); a01 = fmaf(c0, va.y, a01);
    a10 = fmaf(c0, va.z, a10); a11 = fmaf(c0, va.w, a11);
    a00 = fmaf(c1, vb.x, a00); a01 = fmaf(c1, vb.y, a01);
    a10 = fmaf(c1, vb.z, a10); a11 = fmaf(c1, vb.w, a11);
    a00 = fmaf(c2, vc.x, a00); a01 = fmaf(c2, vc.y, a01);
    a10 = fmaf(c2, vc.z, a10); a11 = fmaf(c2, vc.w, a11);
    a00 = fmaf(c3, vd.x, a00); a01 = fmaf(c3, vd.y, a01);
    a10 = fmaf(c3, vd.z, a10); a11 = fmaf(c3, vd.w, a11);
  }
  float p00 = a00 / 3.0f, p01 = a01 / 3.0f, p10 = a10 / 3.0f, p11 = a11 / 3.0f;
  out[(t0 << 9) + l] = p00;
  out[((t0 + 1) << 9) + l] = p10;
  out[HALF_N + (t0 << 9) + l] = p01;
  out[HALF_N + ((t0 + 1) << 9) + l] = p11;
  float s0 = p00 + p10, q0 = fmaf(p00, p00, p10 * p10);
  float s1 = p01 + p11, q1 = fmaf(p01, p01, p11 * p11);
  for (int off = 32; off > 0; off >>= 1) {
    s0 += __shfl_down(s0, off);
    q0 += __shfl_down(q0, off);
    s1 += __shfl_down(s1, off);
    q1 += __shfl_down(q1, off);
  }
  __shared__ float red[4][4];
  int wave = tid >> 6;
  if ((tid & 63) == 0) {
    red[wave][0] = s0; red[wave][1] = q0; red[wave][2] = s1; red[wave][3] = q1;
  }
  __syncthreads();
  if (tid == 0) {
    float a0 = 0.f, a1 = 0.f, a2 = 0.f, a3 = 0.f;
    for (int wv = 0; wv < 4; ++wv) {
      a0 += red[wv][0]; a1 += red[wv][1]; a2 += red[wv][2]; a3 += red[wv][3];
    }
    partial[blockIdx.x * 4 + 0] = a0;
    partial[blockIdx.x * 4 + 1] = a1;
    partial[blockIdx.x * 4 + 2] = a2;
    partial[blockIdx.x * 4 + 3] = a3;
  }
}

// Fused stats + noise: redundant partial reduce -> (std0,std1), then threefry noise.
// element i -> threefry2x32(key=(0,42), ctr=(0,i)), bits = o0^o1
__global__ __launch_bounds__(256) void noise_kernel(float* __restrict__ out,
                                                    const float* __restrict__ partial) {
  int tid = threadIdx.x;
  const float4* pq = (const float4*)partial;  // 512 quads {s0,q0,s1,q1}
  float4 pa = pq[tid];
  float4 pb = pq[tid + 256];
  float s0 = pa.x + pb.x, q0 = pa.y + pb.y, s1 = pa.z + pb.z, q1 = pa.w + pb.w;
  for (int off = 32; off > 0; off >>= 1) {
    s0 += __shfl_down(s0, off);
    q0 += __shfl_down(q0, off);
    s1 += __shfl_down(s1, off);
    q1 += __shfl_down(q1, off);
  }
  __shared__ float red[4][4];
  int wave = tid >> 6;
  if ((tid & 63) == 0) {
    red[wave][0] = s0; red[wave][1] = q0; red[wave][2] = s1; red[wave][3] = q1;
  }
  __syncthreads();
  float S = red[0][0] + red[1][0] + red[2][0] + red[3][0];
  float Q = red[0][1] + red[1][1] + red[2][1] + red[3][1];
  float S2 = red[0][2] + red[1][2] + red[2][2] + red[3][2];
  float Q2 = red[0][3] + red[1][3] + red[2][3] + red[3][3];
  const float invN = 1.0f / 262144.0f;
  float m0 = S * invN, m1 = S2 * invN;
  float std0 = __fsqrt_rn(fmaxf(Q * invN - m0 * m0, 0.0f));
  float std1 = __fsqrt_rn(fmaxf(Q2 * invN - m1 * m1, 0.0f));

  int i = blockIdx.x * 256 + tid;  // < 524288
  uint32_t x0 = 0u;
  uint32_t x1 = (uint32_t)i;
  const uint32_t k0 = 0u, k1 = 42u;
  const uint32_t k2 = k0 ^ k1 ^ 0x1BD11BDAu;
  x0 += k0; x1 += k1;
#define QR(r) x0 += x1; x1 = rotl32(x1, r); x1 ^= x0;
  QR(13) QR(15) QR(26) QR(6)
  x0 += k1; x1 += k2 + 1u;
  QR(17) QR(29) QR(16) QR(24)
  x0 += k2; x1 += k0 + 2u;
  QR(13) QR(15) QR(26) QR(6)
  x0 += k0; x1 += k1 + 3u;
  QR(17) QR(29) QR(16) QR(24)
  x0 += k1; x1 += k2 + 4u;
  QR(13) QR(15) QR(26) QR(6)
  x0 += k2; x1 += k0 + 5u;
#undef QR
  uint32_t bits = x0 ^ x1;
  const float lo = __uint_as_float(0xBF7FFFFFu);  // nextafter(-1,0)
  float f = __uint_as_float((bits >> 9) | 0x3F800000u) - 1.0f;
  float u = fmaxf(lo, __fadd_rn(__fmul_rn(f, 2.0f), lo));
  const float sqrt2 = 1.41421356237309515f;
  out[i] += (i < HALF_N ? std0 : std1) * (sqrt2 * erfinv_xla(u));
}

extern "C" void kernel_launch(void* const* d_in, const int* in_sizes, int n_in,
                              void* d_out, int out_size, void* d_ws, size_t ws_size,
                              hipStream_t stream) {
  const float* x = (const float*)d_in[0];
  float* ws = (float*)d_ws;
  float* Cy      = ws;
  float* Vt      = ws + 262144;   // 4 partials x 524288
  float* partial = ws + 2359296;
  float* out = (float*)d_out;

  init_kernel<<<1024, 256, 0, stream>>>(Cy);
  stageB_kernel<<<2048, 128, 0, stream>>>(x, Cy, Vt);
  stageC_kernel<<<512, 256, 0, stream>>>(Cy, Vt, out, partial);
  noise_kernel<<<2048, 256, 0, stream>>>(out, partial);
}

// Round 14
// 133.558 us; speedup vs baseline: 1.1457x; 1.1457x over previous
//
#include <hip/hip_runtime.h>
#include <stdint.h>
#include <math.h>

// PhysicsForwardModel: B=2, Nz=Nx=128, Ly=Lx=512.
// out[b,t,l] = (1/3) * sum_j Cy[j,l] * sum_k cos(F[k,j]*t) * a[k] * (Cy[:,:128] x[b] Cy[:,128:256]^T)[k,j]
//              + std_b * N(0,1)  (JAX threefry key=42, partitionable counters, XLA erfinv)
// R14: R9's proven phase-C (1 cos per (k,t), 8-wide ILP) with grid k-halved to
// 1024 blocks -> 8 waves/SIMD (R9 filled only half the wave slots; trans pipe
// duty was 66%). Phase B = R13's verified Chebyshev recurrence (no cos, no
// table-latency). Two V k-partials summed in stageC's gather.

#define HALF_N 262144  // 512*512 per-batch elements
#define PI_F 3.14159274101257324f

// ws layout (floats): Cy [0..262144) [k][n]; Vt [262144..1310720) 2 partials x
// [j][b][t]; partial [1310720..1312768)

__device__ __forceinline__ uint32_t rotl32(uint32_t v, int r) {
  return (v << r) | (v >> (32 - r));
}

// XLA ErfInv32 (Giles) -- matches reference's lax.erf_inv
__device__ __forceinline__ float erfinv_xla(float x) {
  float w = -log1pf(__fmul_rn(-x, x));
  float p;
  if (w < 5.0f) {
    w = w - 2.5f;
    p = 2.81022636e-08f;
    p = fmaf(p, w, 3.43273939e-07f);
    p = fmaf(p, w, -3.5233877e-06f);
    p = fmaf(p, w, -4.39150654e-06f);
    p = fmaf(p, w, 0.00021858087f);
    p = fmaf(p, w, -0.00125372503f);
    p = fmaf(p, w, -0.00417768164f);
    p = fmaf(p, w, 0.246640727f);
    p = fmaf(p, w, 1.50140941f);
  } else {
    w = __fsqrt_rn(w) - 3.0f;
    p = -0.000200214257f;
    p = fmaf(p, w, 0.000100950558f);
    p = fmaf(p, w, 0.00134934322f);
    p = fmaf(p, w, -0.00367342844f);
    p = fmaf(p, w, 0.00573950773f);
    p = fmaf(p, w, -0.0076224613f);
    p = fmaf(p, w, 0.00943887047f);
    p = fmaf(p, w, 1.00167406f);
    p = fmaf(p, w, 2.83297682f);
  }
  return p * x;
}

// Cy[k,n] = sc(k) * 2 * cos(pi*(2n+1)*k/1024)
__device__ __forceinline__ float cy_elem(float n2p1, float kf, float sc) {
  float t1 = __fmul_rn(PI_F, n2p1);
  float arg = __fmul_rn(t1, kf) * (1.0f / 1024.0f);
  return __fmul_rn(sc, __fmul_rn(2.0f, __cosf(arg)));
}

// Materialize Cy [k][n] (used by stageB phase A row loads + stageC columns).
__global__ __launch_bounds__(256) void init_kernel(float* __restrict__ Cy) {
  int idx = blockIdx.x * 256 + threadIdx.x;  // < 262144
  const float s0c = 1.0f / __fsqrt_rn(2048.0f);
  int k = idx >> 9, n = idx & 511;
  float sc = (k == 0) ? s0c : 0.03125f;
  Cy[idx] = cy_elem((float)(2 * n + 1), (float)k, sc);
}

// stageB, block = (j, kh) (grid 1024, 512 threads):
//   A  (tid<128): cyl[jj] = Cy[j,128+jj]  (one table row)
//   A2 (tid<256): us[b*128+i] = sum_jj x[b,i,jj]*cyl[jj]
//   B  (tid<256): k=kh*256+tid: m[b,k] via Chebyshev over i (2 cos total);
//                 fs[tid]=F[k,j]; msf float2
//   C  (lane=t):  V_kh[j,b,t] = sum_{256 k} cos(fs*t)*msf  (8-wide ILP, R9 body)
__global__ __launch_bounds__(512, 8) void stageB_kernel(const float* __restrict__ x,
                                                        const float* __restrict__ Cy,
                                                        float* __restrict__ Vt) {
  __shared__ float cyl[128];
  __shared__ float us[256];
  __shared__ float fs[256];
  __shared__ float msf[512];
  int j = blockIdx.x >> 1;
  int kh = blockIdx.x & 1;
  int kbase = kh << 8;
  int tid = threadIdx.x;
  float jf = (float)j;
  const float s0c = 1.0f / __fsqrt_rn(2048.0f);
  if (tid < 128) cyl[tid] = Cy[(j << 9) + 128 + tid];
  __syncthreads();
  if (tid < 256) {
    int b = tid >> 7, i = tid & 127;
    const float* xr = x + (b * 128 + i) * 128;
    float accA = 0.0f, accB = 0.0f;
    for (int jj = 0; jj < 128; jj += 8) {
      float4 xa = *(const float4*)&xr[jj];
      float4 xb = *(const float4*)&xr[jj + 4];
      float4 ca = *(const float4*)&cyl[jj];
      float4 cb = *(const float4*)&cyl[jj + 4];
      accA = fmaf(xa.x, ca.x, accA); accB = fmaf(xa.y, ca.y, accB);
      accA = fmaf(xa.z, ca.z, accA); accB = fmaf(xa.w, ca.w, accB);
      accA = fmaf(xb.x, cb.x, accA); accB = fmaf(xb.y, cb.y, accB);
      accA = fmaf(xb.z, cb.z, accA); accB = fmaf(xb.w, cb.w, accB);
    }
    us[tid] = accA + accB;
  }
  __syncthreads();
  if (tid < 256) {
    int k = kbase + tid;
    float kf = (float)k;
    const float w0 = PI_F / 512.0f;  // exact pow2 scale of pi_f
    float ky = __fmul_rn(kf, w0);    // Chebyshev step
    float kx = __fmul_rn(jf, w0);
    fs[tid] = __fsqrt_rn(__fadd_rn(__fmul_rn(ky, ky), __fmul_rn(kx, kx)));
    // theta_i = (2i+1)*pi*k/1024 = ky/2 + i*ky; c_{-1} = c_0 = cos(ky/2)
    float c0i = __cosf(__fmul_rn(ky, 0.5f));
    float d = __fmul_rn(2.0f, __cosf(ky));
    float sc = (k == 0) ? s0c : 0.03125f;
    float a_k = __fmul_rn(sc, __fmul_rn(2.0f, c0i));  // a[k] = Cy[k,0]
    float cm1 = c0i, cc = c0i;
    float r0 = cc * us[0], r1 = cc * us[128];
    for (int i = 1; i < 128; ++i) {
      float cn = fmaf(d, cc, -cm1);
      cm1 = cc; cc = cn;
      r0 = fmaf(cc, us[i], r0);
      r1 = fmaf(cc, us[128 + i], r1);
    }
    float s2x = __fmul_rn(sc, 2.0f);
    msf[2 * tid] = __fmul_rn(a_k, __fmul_rn(s2x, r0));
    msf[2 * tid + 1] = __fmul_rn(a_k, __fmul_rn(s2x, r1));
  }
  __syncthreads();
  float tf = (float)tid;
  float acc0 = 0.f, acc1 = 0.f, acc2 = 0.f, acc3 = 0.f;
  for (int k0 = 0; k0 < 256; k0 += 8) {
    float4 f0 = *(const float4*)&fs[k0];
    float4 f1 = *(const float4*)&fs[k0 + 4];
    float4 m0 = *(const float4*)&msf[2 * k0];
    float4 m1 = *(const float4*)&msf[2 * k0 + 4];
    float4 m2 = *(const float4*)&msf[2 * k0 + 8];
    float4 m3 = *(const float4*)&msf[2 * k0 + 12];
    float ph0 = __cosf(__fmul_rn(f0.x, tf));  // arg bit-matches ref's f32 F*t
    float ph1 = __cosf(__fmul_rn(f0.y, tf));
    float ph2 = __cosf(__fmul_rn(f0.z, tf));
    float ph3 = __cosf(__fmul_rn(f0.w, tf));
    float ph4 = __cosf(__fmul_rn(f1.x, tf));
    float ph5 = __cosf(__fmul_rn(f1.y, tf));
    float ph6 = __cosf(__fmul_rn(f1.z, tf));
    float ph7 = __cosf(__fmul_rn(f1.w, tf));
    acc0 = fmaf(ph0, m0.x, acc0); acc1 = fmaf(ph0, m0.y, acc1);
    acc2 = fmaf(ph1, m0.z, acc2); acc3 = fmaf(ph1, m0.w, acc3);
    acc0 = fmaf(ph2, m1.x, acc0); acc1 = fmaf(ph2, m1.y, acc1);
    acc2 = fmaf(ph3, m1.z, acc2); acc3 = fmaf(ph3, m1.w, acc3);
    acc0 = fmaf(ph4, m2.x, acc0); acc1 = fmaf(ph4, m2.y, acc1);
    acc2 = fmaf(ph5, m2.z, acc2); acc3 = fmaf(ph5, m2.w, acc3);
    acc0 = fmaf(ph6, m3.x, acc0); acc1 = fmaf(ph6, m3.y, acc1);
    acc2 = fmaf(ph7, m3.z, acc2); acc3 = fmaf(ph7, m3.w, acc3);
  }
  int base = (kh << 19) + (j << 10);
  Vt[base + tid] = acc0 + acc2;
  Vt[base + 512 + tid] = acc1 + acc3;
}

// stageC: out[b,t,l] = (1/3) * sum_j Cy[j,l] * (V0+V1)[j,b,t]; Cy table coalesced.
__global__ __launch_bounds__(256, 4) void stageC_kernel(const float* __restrict__ Cy,
                                                        const float* __restrict__ Vt,
                                                        float* __restrict__ out,
                                                        float* __restrict__ partial) {
  __shared__ float vq[2048];  // [j][4] = {b0t0, b1t0, b0t1, b1t1}
  int tpair = blockIdx.x >> 1;
  int lhalf = blockIdx.x & 1;
  int t0 = tpair << 1;
  int tid = threadIdx.x;
#pragma unroll
  for (int r = 0; r < 2; ++r) {
    int j = tid + (r << 8);
    const float* b0 = Vt + (j << 10);
    const float* b1 = b0 + 524288;
    vq[(j << 2) + 0] = b0[t0] + b1[t0];
    vq[(j << 2) + 1] = b0[512 + t0] + b1[512 + t0];
    vq[(j << 2) + 2] = b0[t0 + 1] + b1[t0 + 1];
    vq[(j << 2) + 3] = b0[512 + t0 + 1] + b1[512 + t0 + 1];
  }
  __syncthreads();
  int l = (lhalf << 8) + tid;
  float a00 = 0.f, a01 = 0.f, a10 = 0.f, a11 = 0.f;
  for (int j = 0; j < 512; j += 4) {
    float c0 = Cy[(j << 9) + l];
    float c1 = Cy[((j + 1) << 9) + l];
    float c2 = Cy[((j + 2) << 9) + l];
    float c3 = Cy[((j + 3) << 9) + l];
    float4 va = *(const float4*)&vq[j << 2];
    float4 vb = *(const float4*)&vq[(j + 1) << 2];
    float4 vc = *(const float4*)&vq[(j + 2) << 2];
    float4 vd = *(const float4*)&vq[(j + 3) << 2];
    a00 = fmaf(c0, va.x, a00); a01 = fmaf(c0, va.y, a01);
    a10 = fmaf(c0, va.z, a10); a11 = fmaf(c0, va.w, a11);
    a00 = fmaf(c1, vb.x, a00); a01 = fmaf(c1, vb.y, a01);
    a10 = fmaf(c1, vb.z, a10); a11 = fmaf(c1, vb.w, a11);
    a00 = fmaf(c2, vc.x, a00); a01 = fmaf(c2, vc.y, a01);
    a10 = fmaf(c2, vc.z, a10); a11 = fmaf(c2, vc.w, a11);
    a00 = fmaf(c3, vd.x, a00); a01 = fmaf(c3, vd.y, a01);
    a10 = fmaf(c3, vd.z, a10); a11 = fmaf(c3, vd.w, a11);
  }
  float p00 = a00 / 3.0f, p01 = a01 / 3.0f, p10 = a10 / 3.0f, p11 = a11 / 3.0f;
  out[(t0 << 9) + l] = p00;
  out[((t0 + 1) << 9) + l] = p10;
  out[HALF_N + (t0 << 9) + l] = p01;
  out[HALF_N + ((t0 + 1) << 9) + l] = p11;
  float s0 = p00 + p10, q0 = fmaf(p00, p00, p10 * p10);
  float s1 = p01 + p11, q1 = fmaf(p01, p01, p11 * p11);
  for (int off = 32; off > 0; off >>= 1) {
    s0 += __shfl_down(s0, off);
    q0 += __shfl_down(q0, off);
    s1 += __shfl_down(s1, off);
    q1 += __shfl_down(q1, off);
  }
  __shared__ float red[4][4];
  int wave = tid >> 6;
  if ((tid & 63) == 0) {
    red[wave][0] = s0; red[wave][1] = q0; red[wave][2] = s1; red[wave][3] = q1;
  }
  __syncthreads();
  if (tid == 0) {
    float a0 = 0.f, a1 = 0.f, a2 = 0.f, a3 = 0.f;
    for (int wv = 0; wv < 4; ++wv) {
      a0 += red[wv][0]; a1 += red[wv][1]; a2 += red[wv][2]; a3 += red[wv][3];
    }
    partial[blockIdx.x * 4 + 0] = a0;
    partial[blockIdx.x * 4 + 1] = a1;
    partial[blockIdx.x * 4 + 2] = a2;
    partial[blockIdx.x * 4 + 3] = a3;
  }
}

// Fused stats + noise: redundant partial reduce -> (std0,std1), then threefry noise.
// element i -> threefry2x32(key=(0,42), ctr=(0,i)), bits = o0^o1
__global__ __launch_bounds__(256) void noise_kernel(float* __restrict__ out,
                                                    const float* __restrict__ partial) {
  int tid = threadIdx.x;
  const float4* pq = (const float4*)partial;  // 512 quads {s0,q0,s1,q1}
  float4 pa = pq[tid];
  float4 pb = pq[tid + 256];
  float s0 = pa.x + pb.x, q0 = pa.y + pb.y, s1 = pa.z + pb.z, q1 = pa.w + pb.w;
  for (int off = 32; off > 0; off >>= 1) {
    s0 += __shfl_down(s0, off);
    q0 += __shfl_down(q0, off);
    s1 += __shfl_down(s1, off);
    q1 += __shfl_down(q1, off);
  }
  __shared__ float red[4][4];
  int wave = tid >> 6;
  if ((tid & 63) == 0) {
    red[wave][0] = s0; red[wave][1] = q0; red[wave][2] = s1; red[wave][3] = q1;
  }
  __syncthreads();
  float S = red[0][0] + red[1][0] + red[2][0] + red[3][0];
  float Q = red[0][1] + red[1][1] + red[2][1] + red[3][1];
  float S2 = red[0][2] + red[1][2] + red[2][2] + red[3][2];
  float Q2 = red[0][3] + red[1][3] + red[2][3] + red[3][3];
  const float invN = 1.0f / 262144.0f;
  float m0 = S * invN, m1 = S2 * invN;
  float std0 = __fsqrt_rn(fmaxf(Q * invN - m0 * m0, 0.0f));
  float std1 = __fsqrt_rn(fmaxf(Q2 * invN - m1 * m1, 0.0f));

  int i = blockIdx.x * 256 + tid;  // < 524288
  uint32_t x0 = 0u;
  uint32_t x1 = (uint32_t)i;
  const uint32_t k0 = 0u, k1 = 42u;
  const uint32_t k2 = k0 ^ k1 ^ 0x1BD11BDAu;
  x0 += k0; x1 += k1;
#define QR(r) x0 += x1; x1 = rotl32(x1, r); x1 ^= x0;
  QR(13) QR(15) QR(26) QR(6)
  x0 += k1; x1 += k2 + 1u;
  QR(17) QR(29) QR(16) QR(24)
  x0 += k2; x1 += k0 + 2u;
  QR(13) QR(15) QR(26) QR(6)
  x0 += k0; x1 += k1 + 3u;
  QR(17) QR(29) QR(16) QR(24)
  x0 += k1; x1 += k2 + 4u;
  QR(13) QR(15) QR(26) QR(6)
  x0 += k2; x1 += k0 + 5u;
#undef QR
  uint32_t bits = x0 ^ x1;
  const float lo = __uint_as_float(0xBF7FFFFFu);  // nextafter(-1,0)
  float f = __uint_as_float((bits >> 9) | 0x3F800000u) - 1.0f;
  float u = fmaxf(lo, __fadd_rn(__fmul_rn(f, 2.0f), lo));
  const float sqrt2 = 1.41421356237309515f;
  out[i] += (i < HALF_N ? std0 : std1) * (sqrt2 * erfinv_xla(u));
}

extern "C" void kernel_launch(void* const* d_in, const int* in_sizes, int n_in,
                              void* d_out, int out_size, void* d_ws, size_t ws_size,
                              hipStream_t stream) {
  const float* x = (const float*)d_in[0];
  float* ws = (float*)d_ws;
  float* Cy      = ws;
  float* Vt      = ws + 262144;   // 2 partials x 524288
  float* partial = ws + 1310720;
  float* out = (float*)d_out;

  init_kernel<<<1024, 256, 0, stream>>>(Cy);
  stageB_kernel<<<1024, 512, 0, stream>>>(x, Cy, Vt);
  stageC_kernel<<<512, 256, 0, stream>>>(Cy, Vt, out, partial);
  noise_kernel<<<2048, 256, 0, stream>>>(out, partial);
}